// Round 6
// baseline (283.722 us; speedup 1.0000x reference)
//
#include <hip/hip_runtime.h>

#define NT 256
#define RCHUNK 32
#define NSLOT 32
#define AC 4   // leading-column pad (16B-aligned halo)

typedef float f2 __attribute__((ext_vector_type(2)));
typedef float f4v __attribute__((ext_vector_type(4)));

__device__ __forceinline__ void gll16(const float* g, float* l) {
    __builtin_amdgcn_global_load_lds(
        (const __attribute__((address_space(1))) void*)g,
        (__attribute__((address_space(3))) void*)l, 16, 0, 0);
}
__device__ __forceinline__ void gll4(const float* g, float* l) {
    __builtin_amdgcn_global_load_lds(
        (const __attribute__((address_space(1))) void*)g,
        (__attribute__((address_space(3))) void*)l, 4, 0, 0);
}

__device__ __forceinline__ float ccval(float sI, float sJ, float sII, float sJJ,
                                       float sIJ, float inv_ws) {
    float cross = fmaf(-(sI * sJ), inv_ws, sIJ);
    float iv    = fmaf(-(sI * sI), inv_ws, sII);
    float jv    = fmaf(-(sJ * sJ), inv_ws, sJJ);
    float den   = fmaf(iv, jv, 1e-8f);
    return (cross * cross) * __builtin_amdgcn_rcpf(den);
}

// Stage phase k (P rows) of J (and I if S==1) via global_load_lds; I for S>=2
// via reg round-trip. Rows outside image/sweep get zero-writes.
template<int W, int WIN, int S, int P>
__device__ __forceinline__ void stage_phase(
    float* __restrict__ smem, int parity, int k, int t,
    const float* __restrict__ Jb, const float* __restrict__ Yb, int r0)
{
    constexpr int HW = WIN / 2;
    constexpr int T = RCHUNK + 2 * HW;
    constexpr int ROWSZ = W + 16;
    constexpr bool B16 = (W >= 256);
    constexpr int SEGW = B16 ? 256 : 64;
    constexpr int SEGS = W / SEGW;
    constexpr int NARR = (S == 1) ? 2 : 1;
    int wv = t >> 6, ln = t & 63;
    int fl = 0;
#pragma unroll
    for (int p = 0; p < P; ++p) {
        int rr = k * P + p;
        int r = r0 - HW + rr;
        bool valid = (rr < T) && (r >= 0) && (r < W);
        float* base = smem + (size_t)((parity * P + p) * 2) * ROWSZ;  // arr0 = I
#pragma unroll
        for (int a = 0; a < NARR; ++a) {
            const float* srow;
            float* drow;
            if (a == NARR - 1) { srow = Jb + (long)r * W;   drow = base + ROWSZ; }
            else               { srow = Yb + (long)r * 512; drow = base; }
#pragma unroll
            for (int sg = 0; sg < SEGS; ++sg) {
                if ((fl & 3) == wv) {
                    if (valid) {
                        if constexpr (B16) gll16(srow + sg * 256 + 4 * ln, drow + AC + sg * 256);
                        else               gll4 (srow + sg * 64 + ln,      drow + AC + sg * 64);
                    } else {
                        if constexpr (B16) {
                            f4v z = {0.f, 0.f, 0.f, 0.f};
                            *(f4v*)(drow + AC + sg * 256 + 4 * ln) = z;
                        } else {
                            drow[AC + sg * 64 + ln] = 0.f;
                        }
                    }
                }
                ++fl;
            }
        }
        if constexpr (S >= 2) {
            if (t < W) {
                float v = 0.f;
                if (valid) {
                    if constexpr (S == 2) {
                        const float* pp = Yb + (long)(2 * r) * 512 + 2 * t;
                        f2 a2 = *(const f2*)pp;
                        f2 b2 = *(const f2*)(pp + 512);
                        v = 0.25f * ((a2.x + a2.y) + (b2.x + b2.y));
                    } else {
                        constexpr int OFF = (S - 2) / 2;
                        const float* pp = Yb + (long)(S * r + OFF) * 512 + (S * t + OFF);
                        v = 0.25f * ((pp[0] + pp[1]) + (pp[512] + pp[513]));
                    }
                }
                base[AC + t] = v;
            }
        }
    }
}

// CPT columns per thread (col = t + c*NT); all ring indices compile-time.
template<int W, int WIN, int P, int BASE, int CPT>
__device__ __forceinline__ void compute_rows(
    const float* __restrict__ smem, int parity, int k, int t,
    float (&rI)[CPT][WIN], float (&rJ)[CPT][WIN], float (&rII)[CPT][WIN],
    float (&rJJ)[CPT][WIN], float (&rIJ)[CPT][WIN],
    float (&vI)[CPT], float (&vJ)[CPT], float (&vII)[CPT],
    float (&vJJ)[CPT], float (&vIJ)[CPT],
    float& l2acc, float& ccacc)
{
    constexpr int HW = WIN / 2;
    constexpr int T = RCHUNK + 2 * HW;
    constexpr int ROWSZ = W + 16;
    constexpr int NB = (WIN + 2) / 2;
    constexpr float INV_WS = 1.0f / (float)(WIN * WIN);
#pragma unroll
    for (int u = 0; u < P; ++u) {
        int rr = k * P + u;
        const float* bI = smem + (size_t)((parity * P + u) * 2) * ROWSZ;
        const float* bJ = bI + ROWSZ;
        if (rr < T) {
#pragma unroll
            for (int c = 0; c < CPT; ++c) {
                int col = t + c * NT;
                if (CPT * NT <= W || col < W) {
                    int START = col - HW + AC;
                    int e0 = START & ~1;
                    bool sh = (START & 1) != 0;
                    float LI[2 * NB], LJ[2 * NB];
#pragma unroll
                    for (int kk = 0; kk < NB; ++kk) {
                        f2 a2 = *(const f2*)(bI + e0 + 2 * kk);
                        f2 b2 = *(const f2*)(bJ + e0 + 2 * kk);
                        LI[2 * kk] = a2.x; LI[2 * kk + 1] = a2.y;
                        LJ[2 * kk] = b2.x; LJ[2 * kk + 1] = b2.y;
                    }
                    float sIs = 0.f, sJs = 0.f, sIIs = 0.f, sJJs = 0.f, sIJs = 0.f;
#pragma unroll
                    for (int kk = 0; kk < WIN; ++kk) {
                        float I = sh ? LI[kk + 1] : LI[kk];
                        float J = sh ? LJ[kk + 1] : LJ[kk];
                        sIs += I; sJs += J;
                        sIIs = fmaf(I, I, sIIs);
                        sJJs = fmaf(J, J, sJJs);
                        sIJs = fmaf(I, J, sIJs);
                    }
                    if (rr >= HW && rr < HW + RCHUNK) {
                        float Ic = sh ? LI[HW + 1] : LI[HW];
                        float Jc = sh ? LJ[HW + 1] : LJ[HW];
                        float d = Jc - Ic;
                        l2acc = fmaf(d, d, l2acc);
                    }
                    const int SL = (BASE + u) % WIN;     // folds after unroll
                    rI[c][SL] = sIs; rJ[c][SL] = sJs; rII[c][SL] = sIIs;
                    rJJ[c][SL] = sJJs; rIJ[c][SL] = sIJs;
                    vI[c] += sIs; vJ[c] += sJs; vII[c] += sIIs;
                    vJJ[c] += sJJs; vIJ[c] += sIJs;
                    if (rr >= 2 * HW) {
                        ccacc += ccval(vI[c], vJ[c], vII[c], vJJ[c], vIJ[c], INV_WS);
                        const int SO = (BASE + u + 1) % WIN;
                        vI[c] -= rI[c][SO]; vJ[c] -= rJ[c][SO]; vII[c] -= rII[c][SO];
                        vJJ[c] -= rJJ[c][SO]; vIJ[c] -= rIJ[c][SO];
                    }
                }
            }
        }
    }
}

template<int W, int WIN, int S, int P, int CPT>
__device__ void level_block(const float* __restrict__ yh, const float* __restrict__ y,
                            int sub, float* __restrict__ ws_acc, int level, float* smem)
{
    constexpr int HW = WIN / 2;
    constexpr int T = RCHUNK + 2 * HW;
    constexpr int NPH = (T + P - 1) / P;
    constexpr int RES = WIN / P;              // 3 for P=3/WIN=9, else 1
    constexpr int NMACRO = (NPH + RES - 1) / RES;
    constexpr int ROWSZ = W + 16;
    constexpr int SMN = 2 * P * 2 * ROWSZ;

    int b = sub & 31;
    int chunk = sub >> 5;
    int r0 = chunk * RCHUNK;
    const float* Jb = yh + (size_t)b * W * W;
    const float* Yb = y + (size_t)b * 512 * 512;
    int t = threadIdx.x;

    // zero staging region once (covers halos; halos never rewritten)
    for (int i = t; i < SMN; i += NT) smem[i] = 0.f;
    __syncthreads();   // zero-fill must complete before phase-0 staging lands

    float rI[CPT][WIN], rJ[CPT][WIN], rII[CPT][WIN], rJJ[CPT][WIN], rIJ[CPT][WIN];
    float vI[CPT], vJ[CPT], vII[CPT], vJJ[CPT], vIJ[CPT];
#pragma unroll
    for (int c = 0; c < CPT; ++c) {
#pragma unroll
        for (int kk = 0; kk < WIN; ++kk) {
            rI[c][kk] = 0.f; rJ[c][kk] = 0.f; rII[c][kk] = 0.f;
            rJJ[c][kk] = 0.f; rIJ[c][kk] = 0.f;
        }
        vI[c] = 0.f; vJ[c] = 0.f; vII[c] = 0.f; vJJ[c] = 0.f; vIJ[c] = 0.f;
    }
    float l2acc = 0.f, ccacc = 0.f;

    stage_phase<W, WIN, S, P>(smem, 0, 0, t, Jb, Yb, r0);

    for (int m = 0; m < NMACRO; ++m) {
#pragma unroll
        for (int j = 0; j < RES; ++j) {
            int k = m * RES + j;
            // phase-k loads are the ONLY outstanding vmem here -> not a drain
            asm volatile("s_waitcnt vmcnt(0) lgkmcnt(0)" ::: "memory");
            __builtin_amdgcn_s_barrier();
            asm volatile("" ::: "memory");   // keep ds_reads after the barrier
            if (k + 1 < NPH)
                stage_phase<W, WIN, S, P>(smem, (k + 1) & 1, k + 1, t, Jb, Yb, r0);
            if (j == 0)
                compute_rows<W, WIN, P, 0, CPT>(smem, k & 1, k, t, rI, rJ, rII, rJJ, rIJ,
                                                vI, vJ, vII, vJJ, vIJ, l2acc, ccacc);
            else if (j == 1)
                compute_rows<W, WIN, P, (P) % WIN, CPT>(smem, k & 1, k, t, rI, rJ, rII, rJJ, rIJ,
                                                        vI, vJ, vII, vJJ, vIJ, l2acc, ccacc);
            else
                compute_rows<W, WIN, P, (2 * P) % WIN, CPT>(smem, k & 1, k, t, rI, rJ, rII, rJJ, rIJ,
                                                            vI, vJ, vII, vJJ, vIJ, l2acc, ccacc);
        }
    }

#pragma unroll
    for (int off = 32; off > 0; off >>= 1) {
        l2acc += __shfl_down(l2acc, off);
        ccacc += __shfl_down(ccacc, off);
    }
    if ((t & 63) == 0) {
        int slot = (blockIdx.x * 4 + (t >> 6)) & (NSLOT - 1);
        atomicAdd(&ws_acc[(level * 2 + 0) * NSLOT + slot], l2acc);
        atomicAdd(&ws_acc[(level * 2 + 1) * NSLOT + slot], ccacc);
    }
}

__global__ __launch_bounds__(NT)
void hier_loss_kernel(const float* __restrict__ yh0, const float* __restrict__ yh1,
                      const float* __restrict__ yh2, const float* __restrict__ yh3,
                      const float* __restrict__ y, float* ws_acc)
{
    __shared__ float smem[6336];   // max: 2*3*2*(512+16) = 6336 floats = 25.3 KB
    int bid = blockIdx.x;
    // L0: 16 chunks x 32 imgs = 512 | L1: 8x32=256 | L2: 4x32=128 | L3: 2x32=64
    if (bid < 512) {
        level_block<512, 9, 1, 3, 2>(yh0, y, bid, ws_acc, 0, smem);
    } else if (bid < 768) {
        level_block<256, 9, 2, 3, 1>(yh1, y, bid - 512, ws_acc, 1, smem);
    } else if (bid < 896) {
        level_block<128, 7, 4, 7, 1>(yh2, y, bid - 768, ws_acc, 2, smem);
    } else {
        level_block<64, 5, 8, 5, 1>(yh3, y, bid - 896, ws_acc, 3, smem);
    }
}

__global__ void hier_finalize_kernel(const float* __restrict__ ws_acc, float* __restrict__ out)
{
    if (threadIdx.x == 0 && blockIdx.x == 0) {
        const float wts[4] = {1.0f, 0.5f, 0.25f, 0.125f};
        float total = 0.f;
#pragma unroll
        for (int lv = 0; lv < 4; ++lv) {
            float l2s = 0.f, ccs = 0.f;
            for (int s = 0; s < NSLOT; ++s) {
                l2s += ws_acc[(lv * 2 + 0) * NSLOT + s];
                ccs += ws_acc[(lv * 2 + 1) * NSLOT + s];
            }
            float l2  = l2s / 32.0f;
            float ncc = -ccs / (32.0f * 100.0f);
            float ll  = wts[lv] * (l2 + ncc) * 0.5f;
            out[1 + lv] = ll;
            total += ll;
        }
        out[0] = total;
    }
}

extern "C" void kernel_launch(void* const* d_in, const int* in_sizes, int n_in,
                              void* d_out, int out_size, void* d_ws, size_t ws_size,
                              hipStream_t stream)
{
    const float* yh0 = (const float*)d_in[0];
    const float* yh1 = (const float*)d_in[1];
    const float* yh2 = (const float*)d_in[2];
    const float* yh3 = (const float*)d_in[3];
    const float* y   = (const float*)d_in[4];
    float* ws_acc = (float*)d_ws;
    float* out = (float*)d_out;

    hipMemsetAsync(ws_acc, 0, 8 * NSLOT * sizeof(float), stream);
    hier_loss_kernel<<<960, NT, 0, stream>>>(yh0, yh1, yh2, yh3, y, ws_acc);
    hier_finalize_kernel<<<1, 64, 0, stream>>>(ws_acc, out);
}

// Round 7
// 215.740 us; speedup vs baseline: 1.3151x; 1.3151x over previous
//
#include <hip/hip_runtime.h>

#define NT 256
#define RCHUNK 32
#define NSLOT 32
#define RWA 72   // per-wave row buffer stride (floats), fits WIN=9 halo (RW=72)

typedef float f2 __attribute__((ext_vector_type(2)));

__device__ __forceinline__ float ccval(float sI, float sJ, float sII, float sJJ,
                                       float sIJ, float inv_ws) {
    float cross = fmaf(-(sI * sJ), inv_ws, sIJ);
    float iv    = fmaf(-(sI * sI), inv_ws, sII);
    float jv    = fmaf(-(sJ * sJ), inv_ws, sJJ);
    float den   = fmaf(iv, jv, 1e-8f);
    return (cross * cross) * __builtin_amdgcn_rcpf(den);
}

struct St { float J, i0, i1, i2, i3; };

// Wave-autonomous: each 64-lane wave owns 64 cols x RCHUNK rows. Raw rows are
// reg-prefetched (1 row ahead), ds_written to a private LDS slab, fenced with
// lgkmcnt(0) ONLY (no barrier, no vmcnt drain -> prefetch stays in flight).
// Vertical 5-stat sliding window in a register ring, compile-time slots.
template<int W, int WIN, int S>
__device__ void level_wave(const float* __restrict__ yh,
                           const float* __restrict__ y,
                           int sub, float* __restrict__ ws_acc, int level,
                           float* __restrict__ slab, int wid)
{
    constexpr int HW = WIN / 2;
    constexpr int RW = 64 + 2 * HW;
    constexpr int T  = RCHUNK + 2 * HW;
    constexpr int G  = (T + WIN - 1) / WIN;
    constexpr int NIT = G * WIN;
    constexpr int WRAP = RW - 64;
    constexpr int NB = (WIN + 2) / 2;
    constexpr int OFF = (S - 2) / 2;
    constexpr float INV_WS = 1.0f / (float)(WIN * WIN);
    constexpr int STRIPS = W / 64;
    constexpr int CHUNKS = W / RCHUNK;

    int b     = sub / (STRIPS * CHUNKS);
    int rem   = sub - b * (STRIPS * CHUNKS);
    int chunk = rem / STRIPS;
    int strip = rem - chunk * STRIPS;
    int r0 = chunk * RCHUNK;
    int c0 = strip * 64;

    const float* Jb = yh + (size_t)b * W * W;
    const float* Yb = y  + (size_t)b * 512 * 512;

    int l  = threadIdx.x & 63;
    int jA = c0 - HW + l;
    int jB = jA + 64;

    auto fetch1 = [&](int rr, int j, St& s) {
        s.J = 0.f; s.i0 = 0.f; s.i1 = 0.f; s.i2 = 0.f; s.i3 = 0.f;
        int r = r0 - HW + rr;
        if (rr < NIT && r >= 0 && r < W && j >= 0 && j < W) {
            s.J = Jb[(long)r * W + j];
            if constexpr (S == 1) {
                s.i0 = Yb[(long)r * 512 + j];
            } else {
                const float* p = Yb + (long)(S * r + OFF) * 512 + (S * j + OFF);
                s.i0 = p[0]; s.i1 = p[1]; s.i2 = p[512]; s.i3 = p[513];
            }
        }
    };
    auto ival = [&](const St& s) -> float {
        if constexpr (S == 1) return s.i0;
        else return 0.25f * ((s.i0 + s.i1) + (s.i2 + s.i3));
    };

    // register ring (CPT=1 — the proven-clean budget)
    float rI[WIN], rJ[WIN], rII[WIN], rJJ[WIN], rIJ[WIN];
#pragma unroll
    for (int k = 0; k < WIN; ++k) { rI[k]=0.f; rJ[k]=0.f; rII[k]=0.f; rJJ[k]=0.f; rIJ[k]=0.f; }
    float vI=0.f, vJ=0.f, vII=0.f, vJJ=0.f, vIJ=0.f;
    float l2acc = 0.f, ccacc = 0.f;

    St sA, sB;
    fetch1(0, jA, sA);
    sB.J = 0.f; sB.i0 = 0.f; sB.i1 = 0.f; sB.i2 = 0.f; sB.i3 = 0.f;
    if (l < WRAP) fetch1(0, jB, sB);

    for (int g = 0; g < G; ++g) {
#pragma unroll
        for (int u = 0; u < WIN; ++u) {
            int rr = g * WIN + u;
            float* bI = slab + (size_t)(((rr & 1) * 2 + 0) * RWA);
            float* bJ = slab + (size_t)(((rr & 1) * 2 + 1) * RWA);

            // 1) stage row rr (implicit counted vmcnt wait for sA/sB here)
            bI[l] = ival(sA);
            bJ[l] = sA.J;
            if (l < WRAP) { bI[64 + l] = ival(sB); bJ[64 + l] = sB.J; }
            // 2) issue next row's global loads — they stay in flight across the fence
            fetch1(rr + 1, jA, sA);
            if (l < WRAP) fetch1(rr + 1, jB, sB);
            // 3) wave-local LDS fence (writes visible to own lanes' reads); NO vmcnt
            asm volatile("s_waitcnt lgkmcnt(0)" ::: "memory");
            // 4) compute from LDS (vectorized f2 taps, parity select)
            if (rr < T) {
                int e0 = l & ~1;
                bool sh = (l & 1) != 0;
                float LI[2 * NB], LJ[2 * NB];
#pragma unroll
                for (int kk = 0; kk < NB; ++kk) {
                    f2 a2 = *(const f2*)(bI + e0 + 2 * kk);
                    f2 b2 = *(const f2*)(bJ + e0 + 2 * kk);
                    LI[2 * kk] = a2.x; LI[2 * kk + 1] = a2.y;
                    LJ[2 * kk] = b2.x; LJ[2 * kk + 1] = b2.y;
                }
                float sIs=0.f, sJs=0.f, sIIs=0.f, sJJs=0.f, sIJs=0.f;
#pragma unroll
                for (int kk = 0; kk < WIN; ++kk) {
                    float I = sh ? LI[kk + 1] : LI[kk];
                    float J = sh ? LJ[kk + 1] : LJ[kk];
                    sIs += I; sJs += J;
                    sIIs = fmaf(I, I, sIIs);
                    sJJs = fmaf(J, J, sJJs);
                    sIJs = fmaf(I, J, sIJs);
                }
                if (rr >= HW && rr < HW + RCHUNK) {
                    float Ic = sh ? LI[HW + 1] : LI[HW];
                    float Jc = sh ? LJ[HW + 1] : LJ[HW];
                    float d = Jc - Ic;
                    l2acc = fmaf(d, d, l2acc);
                }
                rI[u]=sIs; rJ[u]=sJs; rII[u]=sIIs; rJJ[u]=sJJs; rIJ[u]=sIJs;
                vI+=sIs; vJ+=sJs; vII+=sIIs; vJJ+=sJJs; vIJ+=sIJs;
                if (rr >= 2 * HW) {
                    ccacc += ccval(vI, vJ, vII, vJJ, vIJ, INV_WS);
                    const int uo = (u + 1) % WIN;   // compile-time after unroll
                    vI-=rI[uo]; vJ-=rJ[uo]; vII-=rII[uo]; vJJ-=rJJ[uo]; vIJ-=rIJ[uo];
                }
            }
        }
    }

#pragma unroll
    for (int off = 32; off > 0; off >>= 1) {
        l2acc += __shfl_down(l2acc, off);
        ccacc += __shfl_down(ccacc, off);
    }
    if (l == 0) {
        int slot = wid & (NSLOT - 1);
        atomicAdd(&ws_acc[(level * 2 + 0) * NSLOT + slot], l2acc);
        atomicAdd(&ws_acc[(level * 2 + 1) * NSLOT + slot], ccacc);
    }
}

__global__ __launch_bounds__(NT)
void hier_loss_kernel(const float* __restrict__ yh0, const float* __restrict__ yh1,
                      const float* __restrict__ yh2, const float* __restrict__ yh3,
                      const float* __restrict__ y, float* ws_acc)
{
    __shared__ float smem[4][2][2][RWA];   // [wave][parity][I/J][72] = 4.6 KB
    int wave = threadIdx.x >> 6;
    float* slab = &smem[wave][0][0][0];

    int wid = blockIdx.x * (NT / 64) + wave;
    // L0: 8 strips x 16 chunks x 32 = 4096 | L1: 4x8x32=1024 -> [4096,5120)
    // L2: 2x4x32=256 -> [5120,5376)      | L3: 1x2x32=64   -> [5376,5440)
    if (wid < 4096) {
        level_wave<512, 9, 1>(yh0, y, wid, ws_acc, 0, slab, wid);
    } else if (wid < 5120) {
        level_wave<256, 9, 2>(yh1, y, wid - 4096, ws_acc, 1, slab, wid);
    } else if (wid < 5376) {
        level_wave<128, 7, 4>(yh2, y, wid - 5120, ws_acc, 2, slab, wid);
    } else {
        level_wave<64, 5, 8>(yh3, y, wid - 5376, ws_acc, 3, slab, wid);
    }
}

__global__ void hier_finalize_kernel(const float* __restrict__ ws_acc, float* __restrict__ out)
{
    if (threadIdx.x == 0 && blockIdx.x == 0) {
        const float wts[4] = {1.0f, 0.5f, 0.25f, 0.125f};
        float total = 0.f;
#pragma unroll
        for (int lv = 0; lv < 4; ++lv) {
            float l2s = 0.f, ccs = 0.f;
            for (int s = 0; s < NSLOT; ++s) {
                l2s += ws_acc[(lv * 2 + 0) * NSLOT + s];
                ccs += ws_acc[(lv * 2 + 1) * NSLOT + s];
            }
            float l2  = l2s / 32.0f;
            float ncc = -ccs / (32.0f * 100.0f);
            float ll  = wts[lv] * (l2 + ncc) * 0.5f;
            out[1 + lv] = ll;
            total += ll;
        }
        out[0] = total;
    }
}

extern "C" void kernel_launch(void* const* d_in, const int* in_sizes, int n_in,
                              void* d_out, int out_size, void* d_ws, size_t ws_size,
                              hipStream_t stream)
{
    const float* yh0 = (const float*)d_in[0];
    const float* yh1 = (const float*)d_in[1];
    const float* yh2 = (const float*)d_in[2];
    const float* yh3 = (const float*)d_in[3];
    const float* y   = (const float*)d_in[4];
    float* ws_acc = (float*)d_ws;
    float* out = (float*)d_out;

    hipMemsetAsync(ws_acc, 0, 8 * NSLOT * sizeof(float), stream);
    hier_loss_kernel<<<5440 / (NT / 64), NT, 0, stream>>>(yh0, yh1, yh2, yh3, y, ws_acc);
    hier_finalize_kernel<<<1, 64, 0, stream>>>(ws_acc, out);
}